// Round 2
// baseline (559.035 us; speedup 1.0000x reference)
//
#include <hip/hip_runtime.h>
#include <hip/hip_bf16.h>

#define EPSILON 0.01f
#define BSHIFT 7
#define BSZ 128            // nodes per bucket (128*4 floats = 2 KB LDS accumulator)
#define NB_MAX 1024
#define CHUNK 8192         // edges per block in hist/scatter
#define SPLIT 2            // blocks per bucket in accumulate passes

// ---------------- binned fast path ----------------

// Histogram of row-buckets and col-buckets, LDS-aggregated.
__global__ void __launch_bounds__(256) hist_kernel(
    const int* __restrict__ row, const int* __restrict__ col, long long E,
    unsigned* __restrict__ histR, unsigned* __restrict__ histC, int NB)
{
    __shared__ unsigned hR[NB_MAX], hC[NB_MAX];
    for (int i = threadIdx.x; i < NB; i += blockDim.x) { hR[i] = 0u; hC[i] = 0u; }
    __syncthreads();
    long long base = (long long)blockIdx.x * CHUNK;
    int cnt = (int)min((long long)CHUNK, E - base);
    for (int i = threadIdx.x; i < cnt; i += blockDim.x) {
        atomicAdd(&hR[((unsigned)row[base + i]) >> BSHIFT], 1u);
        atomicAdd(&hC[((unsigned)col[base + i]) >> BSHIFT], 1u);
    }
    __syncthreads();
    for (int i = threadIdx.x; i < NB; i += blockDim.x) {
        if (hR[i]) atomicAdd(&histR[i], hR[i]);
        if (hC[i]) atomicAdd(&histC[i], hC[i]);
    }
}

// Single-block exclusive scan of both histograms -> starts + cursors.
__global__ void __launch_bounds__(1024) scan_kernel(
    const unsigned* __restrict__ histR, const unsigned* __restrict__ histC,
    unsigned* __restrict__ startR, unsigned* __restrict__ startC,
    unsigned* __restrict__ curR, unsigned* __restrict__ curC, int NB)
{
    __shared__ unsigned s[NB_MAX];
    int t = threadIdx.x;
    // --- scan C ---
    unsigned v = (t < NB) ? histC[t] : 0u;
    s[t] = v;
    __syncthreads();
    for (int off = 1; off < NB_MAX; off <<= 1) {
        unsigned u = (t >= off) ? s[t - off] : 0u;
        __syncthreads();
        s[t] += u;
        __syncthreads();
    }
    if (t < NB) { unsigned st = s[t] - v; startC[t] = st; curC[t] = st; }
    if (t == NB - 1) startC[NB] = s[t];
    __syncthreads();
    // --- scan R ---
    v = (t < NB) ? histR[t] : 0u;
    s[t] = v;
    __syncthreads();
    for (int off = 1; off < NB_MAX; off <<= 1) {
        unsigned u = (t >= off) ? s[t - off] : 0u;
        __syncthreads();
        s[t] += u;
        __syncthreads();
    }
    if (t < NB) { unsigned st = s[t] - v; startR[t] = st; curR[t] = st; }
    if (t == NB - 1) startR[NB] = s[t];
}

// Counting-sort scatter, LDS-aggregated range reservation.
// sortedC[k] = pack(e:22 | other_node(row):17<<22 | local_col:7<<39)
// sortedR[k] = pack(e:22 | other_node(col):17<<22 | local_row:7<<39)
__global__ void __launch_bounds__(256) scatter_kernel(
    const int* __restrict__ row, const int* __restrict__ col, long long E,
    unsigned* __restrict__ curR, unsigned* __restrict__ curC,
    unsigned long long* __restrict__ sortedR, unsigned long long* __restrict__ sortedC,
    int NB)
{
    __shared__ unsigned hR[NB_MAX], hC[NB_MAX];
    __shared__ unsigned gR[NB_MAX], gC[NB_MAX];
    __shared__ unsigned short loR[CHUNK], loC[CHUNK];
    for (int i = threadIdx.x; i < NB; i += blockDim.x) { hR[i] = 0u; hC[i] = 0u; }
    __syncthreads();
    long long base = (long long)blockIdx.x * CHUNK;
    int cnt = (int)min((long long)CHUNK, E - base);
    for (int i = threadIdx.x; i < cnt; i += blockDim.x) {
        unsigned r = (unsigned)row[base + i], c = (unsigned)col[base + i];
        loR[i] = (unsigned short)atomicAdd(&hR[r >> BSHIFT], 1u);
        loC[i] = (unsigned short)atomicAdd(&hC[c >> BSHIFT], 1u);
    }
    __syncthreads();
    for (int i = threadIdx.x; i < NB; i += blockDim.x) {
        gR[i] = hR[i] ? atomicAdd(&curR[i], hR[i]) : 0u;
        gC[i] = hC[i] ? atomicAdd(&curC[i], hC[i]) : 0u;
    }
    __syncthreads();
    for (int i = threadIdx.x; i < cnt; i += blockDim.x) {
        long long e = base + i;
        unsigned r = (unsigned)row[e], c = (unsigned)col[e];
        unsigned long long pc = (unsigned long long)e
                              | ((unsigned long long)r << 22)
                              | ((unsigned long long)(c & (BSZ - 1)) << 39);
        sortedC[gC[c >> BSHIFT] + loC[i]] = pc;
        unsigned long long pr = (unsigned long long)e
                              | ((unsigned long long)c << 22)
                              | ((unsigned long long)(r & (BSZ - 1)) << 39);
        sortedR[gR[r >> BSHIFT] + loR[i]] = pr;
    }
}

// Pass 1 (A^T x), col-binned: accumulate into LDS, coarse atomic merge.
__global__ void __launch_bounds__(256) spmvt_binned(
    const float4* __restrict__ boo, const float* __restrict__ x,
    const unsigned long long* __restrict__ sortedC,
    const unsigned* __restrict__ startC,
    float* __restrict__ ATx, int N)
{
    __shared__ float acc[BSZ * 4];
    int b = blockIdx.x / SPLIT, part = blockIdx.x % SPLIT;
    for (int i = threadIdx.x; i < BSZ * 4; i += 256) acc[i] = 0.f;
    __syncthreads();
    unsigned s0 = startC[b], s1 = startC[b + 1];
    unsigned len = s1 - s0;
    unsigned a0 = s0 + (unsigned)(((unsigned long long)len * part) / SPLIT);
    unsigned a1 = s0 + (unsigned)(((unsigned long long)len * (part + 1)) / SPLIT);
    int g = threadIdx.x >> 2, j = threadIdx.x & 3;
    for (unsigned k = a0 + g; k < a1; k += 64) {
        unsigned long long p = sortedC[k];
        unsigned e  = (unsigned)(p & 0x3FFFFFu);
        unsigned r  = (unsigned)((p >> 22) & 0x1FFFFu);
        unsigned c7 = (unsigned)(p >> 39);
        float4 brow = boo[(size_t)e * 4 + j];     // B[e][j][0..3]
        float xj = x[r * 4 + j];
        float4 q;
        q.x = brow.x * xj; q.y = brow.y * xj; q.z = brow.z * xj; q.w = brow.w * xj;
        q.x += __shfl_xor(q.x, 1); q.y += __shfl_xor(q.y, 1);
        q.z += __shfl_xor(q.z, 1); q.w += __shfl_xor(q.w, 1);
        q.x += __shfl_xor(q.x, 2); q.y += __shfl_xor(q.y, 2);
        q.z += __shfl_xor(q.z, 2); q.w += __shfl_xor(q.w, 2);
        float v = (j == 0) ? q.x : (j == 1) ? q.y : (j == 2) ? q.z : q.w;
        atomicAdd(&acc[c7 * 4 + j], v);
    }
    __syncthreads();
    int nb0 = b << BSHIFT;
    for (int i = threadIdx.x; i < BSZ * 4; i += 256) {
        int node = nb0 + (i >> 2);
        if (node < N) {
            float v = acc[i];
            if (v != 0.f) unsafeAtomicAdd(&ATx[node * 4 + (i & 3)], v);
        }
    }
}

// Node pass: v = ATx * mask * diag (in place); out = EPSILON * x * diag
__global__ void __launch_bounds__(256) scale_init_kernel(
    const float* __restrict__ x, const float* __restrict__ mask,
    const float* __restrict__ diag, float* __restrict__ ATx,
    float* __restrict__ out, int N)
{
    int n = blockIdx.x * blockDim.x + threadIdx.x;
    if (n >= N) return;
    const float4* x4 = (const float4*)x;
    const float4* d4 = (const float4*)diag;
    float4* a4 = (float4*)ATx;
    float4* o4 = (float4*)out;
    float m = mask[n];
    float4 xv = x4[n], dv = d4[n], av = a4[n];
    float4 ov;
    ov.x = EPSILON * xv.x * dv.x; ov.y = EPSILON * xv.y * dv.y;
    ov.z = EPSILON * xv.z * dv.z; ov.w = EPSILON * xv.w * dv.w;
    o4[n] = ov;
    float4 sv;
    sv.x = av.x * dv.x * m; sv.y = av.y * dv.y * m;
    sv.z = av.z * dv.z * m; sv.w = av.w * dv.w * m;
    a4[n] = sv;
}

// Pass 2 (A v), row-binned: LDS accumulate, merge (* mask) into out.
__global__ void __launch_bounds__(256) spmv_binned(
    const float4* __restrict__ boo, const float* __restrict__ vv,
    const unsigned long long* __restrict__ sortedR,
    const unsigned* __restrict__ startR,
    const float* __restrict__ mask, float* __restrict__ out, int N)
{
    __shared__ float acc[BSZ * 4];
    int b = blockIdx.x / SPLIT, part = blockIdx.x % SPLIT;
    for (int i = threadIdx.x; i < BSZ * 4; i += 256) acc[i] = 0.f;
    __syncthreads();
    unsigned s0 = startR[b], s1 = startR[b + 1];
    unsigned len = s1 - s0;
    unsigned a0 = s0 + (unsigned)(((unsigned long long)len * part) / SPLIT);
    unsigned a1 = s0 + (unsigned)(((unsigned long long)len * (part + 1)) / SPLIT);
    const float4* v4 = (const float4*)vv;
    int g = threadIdx.x >> 2, i = threadIdx.x & 3;
    for (unsigned k = a0 + g; k < a1; k += 64) {
        unsigned long long p = sortedR[k];
        unsigned e  = (unsigned)(p & 0x3FFFFFu);
        unsigned c  = (unsigned)((p >> 22) & 0x1FFFFu);
        unsigned r7 = (unsigned)(p >> 39);
        float4 bi = boo[(size_t)e * 4 + i];   // B[e][i][0..3]
        float4 v = v4[c];                     // broadcast within 4-lane group
        float m = bi.x * v.x + bi.y * v.y + bi.z * v.z + bi.w * v.w;
        atomicAdd(&acc[r7 * 4 + i], m);
    }
    __syncthreads();
    int nb0 = b << BSHIFT;
    for (int idx = threadIdx.x; idx < BSZ * 4; idx += 256) {
        int node = nb0 + (idx >> 2);
        if (node < N) {
            float v = acc[idx];
            if (v != 0.f) unsafeAtomicAdd(&out[node * 4 + (idx & 3)], v * mask[node]);
        }
    }
}

// ---------------- fallback path (round-1 kernels) ----------------

__global__ void __launch_bounds__(256) spmvt_kernel(
    const float4* __restrict__ boo, const int* __restrict__ row,
    const int* __restrict__ col, const float* __restrict__ x,
    float* __restrict__ ATx, long long E)
{
    long long t = (long long)blockIdx.x * blockDim.x + threadIdx.x;
    long long e = t >> 2;
    int j = (int)(t & 3);
    if (e >= E) return;
    float4 b = boo[e * 4 + j];
    int r = row[e];
    float xj = x[r * 4 + j];
    float4 p;
    p.x = b.x * xj; p.y = b.y * xj; p.z = b.z * xj; p.w = b.w * xj;
    p.x += __shfl_xor(p.x, 1); p.y += __shfl_xor(p.y, 1);
    p.z += __shfl_xor(p.z, 1); p.w += __shfl_xor(p.w, 1);
    p.x += __shfl_xor(p.x, 2); p.y += __shfl_xor(p.y, 2);
    p.z += __shfl_xor(p.z, 2); p.w += __shfl_xor(p.w, 2);
    float v = (j == 0) ? p.x : (j == 1) ? p.y : (j == 2) ? p.z : p.w;
    int c = col[e];
    unsafeAtomicAdd(&ATx[c * 4 + j], v);
}

__global__ void __launch_bounds__(256) spmv_kernel(
    const float4* __restrict__ boo, const int* __restrict__ row,
    const int* __restrict__ col, const float* __restrict__ vv,
    const float* __restrict__ mask, float* __restrict__ out, long long E)
{
    long long t = (long long)blockIdx.x * blockDim.x + threadIdx.x;
    long long e = t >> 2;
    int i = (int)(t & 3);
    if (e >= E) return;
    float4 b = boo[e * 4 + i];
    int c = col[e];
    const float4* v4 = (const float4*)vv;
    float4 v = v4[c];
    float mi = b.x * v.x + b.y * v.y + b.z * v.z + b.w * v.w;
    int r = row[e];
    unsafeAtomicAdd(&out[r * 4 + i], mi * mask[r]);
}

extern "C" void kernel_launch(void* const* d_in, const int* in_sizes, int n_in,
                              void* d_out, int out_size, void* d_ws, size_t ws_size,
                              hipStream_t stream) {
    const float* x    = (const float*)d_in[0];
    const int*   ei   = (const int*)d_in[1];
    const float* boo  = (const float*)d_in[2];
    const float* mask = (const float*)d_in[3];
    const float* diag = (const float*)d_in[4];
    float* out = (float*)d_out;

    int N = in_sizes[0] / 4;
    long long E = in_sizes[1] / 2;
    const int* row = ei;
    const int* col = ei + E;

    int NB = (N + BSZ - 1) >> BSHIFT;
    const int blk = 256;
    int gNode = (N + blk - 1) / blk;

    size_t need = (size_t)E * 16            // sortedC + sortedR (u64 each)
                + (size_t)N * 16            // ATx
                + (size_t)(6 * NB + 2) * 4  // hists, starts, cursors
                + 256;
    bool fast = (ws_size >= need) && (NB <= NB_MAX) && (E < (1LL << 22)) && (N < (1 << 17));

    if (fast) {
        char* w = (char*)d_ws;
        unsigned long long* sortedC = (unsigned long long*)w;          w += (size_t)E * 8;
        unsigned long long* sortedR = (unsigned long long*)w;          w += (size_t)E * 8;
        float* ATx = (float*)w;                                        w += (size_t)N * 16;
        unsigned* histR  = (unsigned*)w;                               w += (size_t)NB * 4;
        unsigned* histC  = (unsigned*)w;                               w += (size_t)NB * 4;
        unsigned* startR = (unsigned*)w;                               w += (size_t)(NB + 1) * 4;
        unsigned* startC = (unsigned*)w;                               w += (size_t)(NB + 1) * 4;
        unsigned* curR   = (unsigned*)w;                               w += (size_t)NB * 4;
        unsigned* curC   = (unsigned*)w;

        hipMemsetAsync(ATx, 0, (size_t)N * 16 + (size_t)NB * 8, stream); // ATx + both hists

        int nblk = (int)((E + CHUNK - 1) / CHUNK);
        hist_kernel<<<nblk, blk, 0, stream>>>(row, col, E, histR, histC, NB);
        scan_kernel<<<1, NB_MAX, 0, stream>>>(histR, histC, startR, startC, curR, curC, NB);
        scatter_kernel<<<nblk, blk, 0, stream>>>(row, col, E, curR, curC, sortedR, sortedC, NB);
        spmvt_binned<<<NB * SPLIT, blk, 0, stream>>>(
            (const float4*)boo, x, sortedC, startC, ATx, N);
        scale_init_kernel<<<gNode, blk, 0, stream>>>(x, mask, diag, ATx, out, N);
        spmv_binned<<<NB * SPLIT, blk, 0, stream>>>(
            (const float4*)boo, ATx, sortedR, startR, mask, out, N);
    } else {
        float* ATx = (float*)d_ws;
        hipMemsetAsync(ATx, 0, (size_t)N * 16, stream);
        long long T = E * 4;
        int gEdge = (int)((T + blk - 1) / blk);
        spmvt_kernel<<<gEdge, blk, 0, stream>>>((const float4*)boo, row, col, x, ATx, E);
        scale_init_kernel<<<gNode, blk, 0, stream>>>(x, mask, diag, ATx, out, N);
        spmv_kernel<<<gEdge, blk, 0, stream>>>((const float4*)boo, row, col, ATx, mask, out, E);
    }
}

// Round 3
// 550.985 us; speedup vs baseline: 1.0146x; 1.0146x over previous
//
#include <hip/hip_runtime.h>
#include <hip/hip_fp16.h>
#include <hip/hip_bf16.h>

#define EPSILON 0.01f

// ---------------- pk_f16 fast path ----------------
// Pass 1: msg_t[e,i] = sum_j B[e][j][i] * x[row[e]][j]; scatter-add (packed f16)
// into ATx_h[col[e]]. 4 lanes per edge, lane j holds B-row j (coalesced float4).
__global__ void __launch_bounds__(256) spmvt_pk(
    const float4* __restrict__ boo,
    const int* __restrict__ row,
    const int* __restrict__ col,
    const float* __restrict__ x,
    __half2* __restrict__ ATx_h,   // [N*2] half2, pre-zeroed
    long long E)
{
    long long t = (long long)blockIdx.x * blockDim.x + threadIdx.x;
    long long e = t >> 2;
    int j = (int)(t & 3);
    if (e >= E) return;

    float4 b = boo[e * 4 + j];            // B[e][j][0..3]
    int r = row[e];
    float xj = x[r * 4 + j];

    float4 q;
    q.x = b.x * xj; q.y = b.y * xj; q.z = b.z * xj; q.w = b.w * xj;
    // butterfly over the 4-lane group: all lanes end with the full msg_t
    q.x += __shfl_xor(q.x, 1); q.y += __shfl_xor(q.y, 1);
    q.z += __shfl_xor(q.z, 1); q.w += __shfl_xor(q.w, 1);
    q.x += __shfl_xor(q.x, 2); q.y += __shfl_xor(q.y, 2);
    q.z += __shfl_xor(q.z, 2); q.w += __shfl_xor(q.w, 2);

    if (j < 2) {                           // 2 pk transactions per edge
        int c = col[e];
        float lo = (j == 0) ? q.x : q.z;
        float hi = (j == 0) ? q.y : q.w;
        __half2 h = __floats2half2_rn(lo, hi);
        unsafeAtomicAdd(&ATx_h[(size_t)c * 2 + j], h);  // global_atomic_pk_add_f16
    }
}

// Node pass: v[n] = (float)ATx_h[n] * mask[n] * diag[n]  (f32 for pass-2 accuracy)
__global__ void __launch_bounds__(256) scale_v_kernel(
    const __half2* __restrict__ ATx_h,
    const float* __restrict__ mask,
    const float* __restrict__ diag,
    float4* __restrict__ v4,
    int N)
{
    int n = blockIdx.x * blockDim.x + threadIdx.x;
    if (n >= N) return;
    float2 a0 = __half22float2(ATx_h[(size_t)n * 2]);
    float2 a1 = __half22float2(ATx_h[(size_t)n * 2 + 1]);
    float m = mask[n];
    const float4* d4 = (const float4*)diag;
    float4 d = d4[n];
    float4 v;
    v.x = a0.x * m * d.x; v.y = a0.y * m * d.y;
    v.z = a1.x * m * d.z; v.w = a1.y * m * d.w;
    v4[n] = v;
}

// Pass 2: msg[e,i] = dot(B[e][i][:], v[col[e]]); scatter-add packed f16 into
// out_h[row[e]]. Lane i computes component i; even lanes commit (i, i+1).
__global__ void __launch_bounds__(256) spmv_pk(
    const float4* __restrict__ boo,
    const int* __restrict__ row,
    const int* __restrict__ col,
    const float4* __restrict__ v4,
    __half2* __restrict__ out_h,   // [N*2] half2, pre-zeroed
    long long E)
{
    long long t = (long long)blockIdx.x * blockDim.x + threadIdx.x;
    long long e = t >> 2;
    int i = (int)(t & 3);
    if (e >= E) return;

    float4 b = boo[e * 4 + i];            // B[e][i][0..3]
    int c = col[e];
    float4 v = v4[c];
    float mi = b.x * v.x + b.y * v.y + b.z * v.z + b.w * v.w;
    float partner = __shfl_xor(mi, 1);    // even lane gets odd lane's component
    if ((i & 1) == 0) {
        int r = row[e];
        __half2 h = __floats2half2_rn(mi, partner);
        unsafeAtomicAdd(&out_h[(size_t)r * 2 + (i >> 1)], h);
    }
}

// Final: out = EPSILON*x*diag + mask*(float)out_h
__global__ void __launch_bounds__(256) finalize_kernel(
    const float* __restrict__ x,
    const float* __restrict__ mask,
    const float* __restrict__ diag,
    const __half2* __restrict__ out_h,
    float4* __restrict__ out4,
    int N)
{
    int n = blockIdx.x * blockDim.x + threadIdx.x;
    if (n >= N) return;
    const float4* x4 = (const float4*)x;
    const float4* d4 = (const float4*)diag;
    float4 xv = x4[n], dv = d4[n];
    float m = mask[n];
    float2 o0 = __half22float2(out_h[(size_t)n * 2]);
    float2 o1 = __half22float2(out_h[(size_t)n * 2 + 1]);
    float4 o;
    o.x = EPSILON * xv.x * dv.x + m * o0.x;
    o.y = EPSILON * xv.y * dv.y + m * o0.y;
    o.z = EPSILON * xv.z * dv.z + m * o1.x;
    o.w = EPSILON * xv.w * dv.w + m * o1.y;
    out4[n] = o;
}

// ---------------- fp32 fallback (round-1 proven path) ----------------
__global__ void __launch_bounds__(256) spmvt_kernel(
    const float4* __restrict__ boo, const int* __restrict__ row,
    const int* __restrict__ col, const float* __restrict__ x,
    float* __restrict__ ATx, long long E)
{
    long long t = (long long)blockIdx.x * blockDim.x + threadIdx.x;
    long long e = t >> 2;
    int j = (int)(t & 3);
    if (e >= E) return;
    float4 b = boo[e * 4 + j];
    int r = row[e];
    float xj = x[r * 4 + j];
    float4 p;
    p.x = b.x * xj; p.y = b.y * xj; p.z = b.z * xj; p.w = b.w * xj;
    p.x += __shfl_xor(p.x, 1); p.y += __shfl_xor(p.y, 1);
    p.z += __shfl_xor(p.z, 1); p.w += __shfl_xor(p.w, 1);
    p.x += __shfl_xor(p.x, 2); p.y += __shfl_xor(p.y, 2);
    p.z += __shfl_xor(p.z, 2); p.w += __shfl_xor(p.w, 2);
    float v = (j == 0) ? p.x : (j == 1) ? p.y : (j == 2) ? p.z : p.w;
    unsafeAtomicAdd(&ATx[(size_t)col[e] * 4 + j], v);
}

__global__ void __launch_bounds__(256) scale_init_kernel(
    const float* __restrict__ x, const float* __restrict__ mask,
    const float* __restrict__ diag, float* __restrict__ ATx,
    float* __restrict__ out, int N)
{
    int n = blockIdx.x * blockDim.x + threadIdx.x;
    if (n >= N) return;
    const float4* x4 = (const float4*)x;
    const float4* d4 = (const float4*)diag;
    float4* a4 = (float4*)ATx;
    float4* o4 = (float4*)out;
    float m = mask[n];
    float4 xv = x4[n], dv = d4[n], av = a4[n];
    float4 ov;
    ov.x = EPSILON * xv.x * dv.x; ov.y = EPSILON * xv.y * dv.y;
    ov.z = EPSILON * xv.z * dv.z; ov.w = EPSILON * xv.w * dv.w;
    o4[n] = ov;
    float4 sv;
    sv.x = av.x * dv.x * m; sv.y = av.y * dv.y * m;
    sv.z = av.z * dv.z * m; sv.w = av.w * dv.w * m;
    a4[n] = sv;
}

__global__ void __launch_bounds__(256) spmv_kernel(
    const float4* __restrict__ boo, const int* __restrict__ row,
    const int* __restrict__ col, const float* __restrict__ vv,
    const float* __restrict__ mask, float* __restrict__ out, long long E)
{
    long long t = (long long)blockIdx.x * blockDim.x + threadIdx.x;
    long long e = t >> 2;
    int i = (int)(t & 3);
    if (e >= E) return;
    float4 b = boo[e * 4 + i];
    int c = col[e];
    const float4* v4 = (const float4*)vv;
    float4 v = v4[c];
    float mi = b.x * v.x + b.y * v.y + b.z * v.z + b.w * v.w;
    int r = row[e];
    unsafeAtomicAdd(&out[(size_t)r * 4 + i], mi * mask[r]);
}

extern "C" void kernel_launch(void* const* d_in, const int* in_sizes, int n_in,
                              void* d_out, int out_size, void* d_ws, size_t ws_size,
                              hipStream_t stream) {
    const float* x    = (const float*)d_in[0];
    const int*   ei   = (const int*)d_in[1];
    const float* boo  = (const float*)d_in[2];
    const float* mask = (const float*)d_in[3];
    const float* diag = (const float*)d_in[4];
    float* out = (float*)d_out;

    int N = in_sizes[0] / 4;
    long long E = in_sizes[1] / 2;
    const int* row = ei;
    const int* col = ei + E;

    const int blk = 256;
    long long T = E * 4;
    int gEdge = (int)((T + blk - 1) / blk);
    int gNode = (N + blk - 1) / blk;

    size_t need = (size_t)N * 32;  // ATx_h (8N) + out_h (8N) + v (16N)
    if (ws_size >= need) {
        char* w = (char*)d_ws;
        __half2* ATx_h = (__half2*)w;            w += (size_t)N * 8;
        __half2* out_h = (__half2*)w;            w += (size_t)N * 8;
        float4*  v4    = (float4*)w;

        // zero both f16 accumulators in one memset (contiguous)
        hipMemsetAsync(ATx_h, 0, (size_t)N * 16, stream);

        spmvt_pk<<<gEdge, blk, 0, stream>>>(
            (const float4*)boo, row, col, x, ATx_h, E);
        scale_v_kernel<<<gNode, blk, 0, stream>>>(ATx_h, mask, diag, v4, N);
        spmv_pk<<<gEdge, blk, 0, stream>>>(
            (const float4*)boo, row, col, v4, out_h, E);
        finalize_kernel<<<gNode, blk, 0, stream>>>(
            x, mask, diag, out_h, (float4*)out, N);
    } else {
        float* ATx = (float*)d_ws;
        hipMemsetAsync(ATx, 0, (size_t)N * 16, stream);
        spmvt_kernel<<<gEdge, blk, 0, stream>>>((const float4*)boo, row, col, x, ATx, E);
        scale_init_kernel<<<gNode, blk, 0, stream>>>(x, mask, diag, ATx, out, N);
        spmv_kernel<<<gEdge, blk, 0, stream>>>((const float4*)boo, row, col, ATx, mask, out, E);
    }
}